// Round 1
// baseline (321.585 us; speedup 1.0000x reference)
//
#include <hip/hip_runtime.h>

#define QSCALE 0.08838834764831845f   // (2*64)^-0.5

typedef __bf16 bf16x8 __attribute__((ext_vector_type(8)));
typedef float  f32x4  __attribute__((ext_vector_type(4)));

__device__ inline bf16x8 load16(const __bf16* p) { return *reinterpret_cast<const bf16x8*>(p); }

__device__ inline void gld_lds16(const void* g, void* l) {
  __builtin_amdgcn_global_load_lds((const __attribute__((address_space(1))) void*)g,
                                   (__attribute__((address_space(3))) void*)l, 16, 0, 0);
}

// ---------------- prep kernels ----------------

// Xc [8192][1536] bf16 = concat(rgb, spec) rows
__global__ void prep_x(const float* __restrict__ rgb, const float* __restrict__ spec,
                       __bf16* __restrict__ Xc) {
  int c = blockIdx.x * 256 + threadIdx.x;       // 8192*192 chunks of 8
  int row = c / 192, seg = c % 192;
  const float* src = (seg < 96) ? (rgb + row * 768 + seg * 8)
                                : (spec + row * 768 + (seg - 96) * 8);
  bf16x8 v;
#pragma unroll
  for (int i = 0; i < 8; ++i) v[i] = (__bf16)src[i];
  *reinterpret_cast<bf16x8*>(Xc + (size_t)c * 8) = v;
}

// Wc [2304][1536] bf16 = [rgb_qkv_w * s | spec_qkv_w * t] with section scales
__global__ void prep_w(const float* __restrict__ wr, const float* __restrict__ wsp,
                       __bf16* __restrict__ Wc) {
  int c = blockIdx.x * 256 + threadIdx.x;       // 2304*192
  int n = c / 192, seg = c % 192;
  bool isR = seg < 96;
  const float* src = isR ? (wr + n * 768 + seg * 8)
                         : (wsp + n * 768 + (seg - 96) * 8);
  float sc = (n < 768) ? QSCALE : (n < 1536) ? 1.0f : (isR ? 1.0f : 0.5f);
  bf16x8 v;
#pragma unroll
  for (int i = 0; i < 8; ++i) v[i] = (__bf16)(src[i] * sc);
  *reinterpret_cast<bf16x8*>(Wc + (size_t)c * 8) = v;
}

__global__ void prep_bias(const float* __restrict__ rb, const float* __restrict__ sb,
                          float* __restrict__ bc) {
  int n = blockIdx.x * 256 + threadIdx.x;       // 2304 exactly
  float sr = (n < 768) ? QSCALE : 1.0f;
  float ss = (n < 768) ? QSCALE : (n < 1536) ? 1.0f : 0.5f;
  bc[n] = sr * rb[n] + ss * sb[n];
}

__global__ void prep_pw(const float* __restrict__ pw, __bf16* __restrict__ Pb) {
  int c = blockIdx.x * 256 + threadIdx.x;       // 768*96
  bf16x8 v;
#pragma unroll
  for (int i = 0; i < 8; ++i) v[i] = (__bf16)pw[(size_t)c * 8 + i];
  *reinterpret_cast<bf16x8*>(Pb + (size_t)c * 8) = v;
}

// ---------------- GEMM: C[M][N] = A[M][K] @ B[N][K]^T ----------------
// MODE 0: scatter to Q/K [bh][l][64] bf16 and V^T [bh][64][l] bf16 (+bias)
// MODE 1: Out f32 [M][768] = C + bias
template <int K, int MODE>
__global__ __launch_bounds__(256) void gemm_bt(const __bf16* __restrict__ A,
                                               const __bf16* __restrict__ Bm,
                                               const float* __restrict__ bias,
                                               __bf16* __restrict__ Qo, __bf16* __restrict__ Ko,
                                               __bf16* __restrict__ Vo, float* __restrict__ Out) {
  __shared__ __bf16 As[128 * 32], Bs[128 * 32];
  const int tid = threadIdx.x;
  const int m0 = blockIdx.y * 128, n0 = blockIdx.x * 128;
  const int wid = tid >> 6, lane = tid & 63, r = lane & 15, g = lane >> 4;
  const int wr = wid >> 1, wc = wid & 1;
  f32x4 acc[4][4] = {};
  const __bf16* gA = A + (size_t)(m0 + (tid >> 2)) * K + (tid & 3) * 8;
  const __bf16* gB = Bm + (size_t)(n0 + (tid >> 2)) * K + (tid & 3) * 8;
  __bf16* lA = As + wid * 512;   // wave-uniform LDS base; HW adds lane*16B
  __bf16* lB = Bs + wid * 512;

  for (int kt = 0; kt < K; kt += 32) {
    gld_lds16(gA + kt, lA);
    gld_lds16(gA + 64 * K + kt, lA + 2048);
    gld_lds16(gB + kt, lB);
    gld_lds16(gB + 64 * K + kt, lB + 2048);
    __syncthreads();
    bf16x8 af[4], bf[4];
#pragma unroll
    for (int i = 0; i < 4; ++i) af[i] = load16(&As[(wr * 64 + i * 16 + r) * 32 + g * 8]);
#pragma unroll
    for (int i = 0; i < 4; ++i) bf[i] = load16(&Bs[(wc * 64 + i * 16 + r) * 32 + g * 8]);
#pragma unroll
    for (int mi = 0; mi < 4; ++mi)
#pragma unroll
      for (int ni = 0; ni < 4; ++ni)
        acc[mi][ni] = __builtin_amdgcn_mfma_f32_16x16x32_bf16(af[mi], bf[ni], acc[mi][ni], 0, 0, 0);
    __syncthreads();
  }

  if (MODE == 0) {
    const int sec = n0 / 768;   // 128 | 768 -> block never straddles sections
#pragma unroll
    for (int mi = 0; mi < 4; ++mi)
#pragma unroll
      for (int ni = 0; ni < 4; ++ni)
#pragma unroll
        for (int j = 0; j < 4; ++j) {
          int i = m0 + wr * 64 + mi * 16 + g * 4 + j;
          int n = n0 + wc * 64 + ni * 16 + r;
          float v = acc[mi][ni][j] + bias[n];
          int b = i >> 10, l = i & 1023;
          int idx = n - sec * 768, h = idx >> 6, d = idx & 63;
          int bh = b * 12 + h;
          if (sec == 0)      Qo[(bh << 16) + (l << 6) + d] = (__bf16)v;
          else if (sec == 1) Ko[(bh << 16) + (l << 6) + d] = (__bf16)v;
          else               Vo[(bh << 16) + (d << 10) + l] = (__bf16)v;
        }
  } else {
#pragma unroll
    for (int mi = 0; mi < 4; ++mi)
#pragma unroll
      for (int ni = 0; ni < 4; ++ni)
#pragma unroll
        for (int j = 0; j < 4; ++j) {
          int i = m0 + wr * 64 + mi * 16 + g * 4 + j;
          int n = n0 + wc * 64 + ni * 16 + r;
          Out[(size_t)i * 768 + n] = acc[mi][ni][j] + bias[n];
        }
  }
}

// ---------------- flash attention ----------------
// grid (96 heads, 4 qblocks) x 256 thr. Each wave owns 64 q-rows.
// Q,K: [bh][1024][64] bf16; V: [bh][64][1024] bf16 (pre-transposed).
// Out Xo: [B=8][L=1024][768] bf16 at column h*64+d.
__global__ __launch_bounds__(256) void attn_fwd(const __bf16* __restrict__ Qg,
                                                const __bf16* __restrict__ Kg,
                                                const __bf16* __restrict__ Vg,
                                                __bf16* __restrict__ Xo) {
  __shared__ __bf16 Pl[4][64 * 72];   // per-wave P buffer, stride 72 (144B, 16B-aligned, 2-way banks)
  const int bh = blockIdx.x, qb = blockIdx.y;
  const int tid = threadIdx.x, wid = tid >> 6, lane = tid & 63, r = lane & 15, g = lane >> 4;
  const int q0 = qb * 256 + wid * 64;
  const __bf16* Qh = Qg + (size_t)bh * 65536;
  const __bf16* Kh = Kg + (size_t)bh * 65536;
  const __bf16* Vh = Vg + (size_t)bh * 65536;
  __bf16* Pw = &Pl[wid][0];

  bf16x8 aq[4][2];
#pragma unroll
  for (int mi = 0; mi < 4; ++mi)
#pragma unroll
    for (int ks = 0; ks < 2; ++ks)
      aq[mi][ks] = load16(&Qh[(q0 + mi * 16 + r) * 64 + ks * 32 + g * 8]);

  f32x4 o[4][4] = {};
  float mrow[4][4], lrow[4][4];
#pragma unroll
  for (int mi = 0; mi < 4; ++mi)
#pragma unroll
    for (int j = 0; j < 4; ++j) { mrow[mi][j] = -1e30f; lrow[mi][j] = 0.f; }

  for (int kv0 = 0; kv0 < 1024; kv0 += 64) {
    // S = Q K^T : D row = local q (g*4+j), col = kv (r)
    f32x4 s[4][4] = {};
#pragma unroll
    for (int ks = 0; ks < 2; ++ks)
#pragma unroll
      for (int ni = 0; ni < 4; ++ni) {
        bf16x8 bk = load16(&Kh[(kv0 + ni * 16 + r) * 64 + ks * 32 + g * 8]);
#pragma unroll
        for (int mi = 0; mi < 4; ++mi)
          s[mi][ni] = __builtin_amdgcn_mfma_f32_16x16x32_bf16(aq[mi][ks], bk, s[mi][ni], 0, 0, 0);
      }
    // online softmax; row lives across 16 lanes (same g) -> shfl_xor 1/2/4/8
#pragma unroll
    for (int mi = 0; mi < 4; ++mi)
#pragma unroll
      for (int j = 0; j < 4; ++j) {
        float mx = fmaxf(fmaxf(s[mi][0][j], s[mi][1][j]), fmaxf(s[mi][2][j], s[mi][3][j]));
#pragma unroll
        for (int dd = 8; dd >= 1; dd >>= 1) mx = fmaxf(mx, __shfl_xor(mx, dd, 64));
        float mn = fmaxf(mrow[mi][j], mx);
        float al = __expf(mrow[mi][j] - mn);
        mrow[mi][j] = mn;
        float rs = 0.f;
#pragma unroll
        for (int ni = 0; ni < 4; ++ni) {
          float p = __expf(s[mi][ni][j] - mn);
          s[mi][ni][j] = p;
          rs += p;
        }
#pragma unroll
        for (int dd = 8; dd >= 1; dd >>= 1) rs += __shfl_xor(rs, dd, 64);
        lrow[mi][j] = lrow[mi][j] * al + rs;
#pragma unroll
        for (int di = 0; di < 4; ++di) o[mi][di][j] *= al;
      }
    // P -> LDS (D-layout) then re-read as A-fragments
#pragma unroll
    for (int mi = 0; mi < 4; ++mi)
#pragma unroll
      for (int ni = 0; ni < 4; ++ni)
#pragma unroll
        for (int j = 0; j < 4; ++j)
          Pw[(mi * 16 + g * 4 + j) * 72 + ni * 16 + r] = (__bf16)s[mi][ni][j];
    // O += P V  (B-operand rows = V^T rows, contiguous in kv)
#pragma unroll
    for (int ks = 0; ks < 2; ++ks) {
      bf16x8 pa[4];
#pragma unroll
      for (int mi = 0; mi < 4; ++mi) pa[mi] = load16(&Pw[(mi * 16 + r) * 72 + ks * 32 + g * 8]);
#pragma unroll
      for (int di = 0; di < 4; ++di) {
        bf16x8 bv = load16(&Vh[(di * 16 + r) * 1024 + kv0 + ks * 32 + g * 8]);
#pragma unroll
        for (int mi = 0; mi < 4; ++mi)
          o[mi][di] = __builtin_amdgcn_mfma_f32_16x16x32_bf16(pa[mi], bv, o[mi][di], 0, 0, 0);
      }
    }
  }

  const int b = bh / 12, h = bh % 12;
#pragma unroll
  for (int mi = 0; mi < 4; ++mi)
#pragma unroll
    for (int di = 0; di < 4; ++di)
#pragma unroll
      for (int j = 0; j < 4; ++j) {
        int q = q0 + mi * 16 + g * 4 + j;
        float v = o[mi][di][j] / lrow[mi][j];
        Xo[((size_t)b * 1024 + q) * 768 + h * 64 + di * 16 + r] = (__bf16)v;
      }
}

// ---------------- launch ----------------

extern "C" void kernel_launch(void* const* d_in, const int* in_sizes, int n_in,
                              void* d_out, int out_size, void* d_ws, size_t ws_size,
                              hipStream_t stream) {
  const float* rgb   = (const float*)d_in[0];
  const float* spec  = (const float*)d_in[1];
  const float* rqkvw = (const float*)d_in[2];
  const float* rqkvb = (const float*)d_in[3];
  const float* sqkvw = (const float*)d_in[4];
  const float* sqkvb = (const float*)d_in[5];
  const float* projw = (const float*)d_in[6];
  const float* projb = (const float*)d_in[7];
  float* out = (float*)d_out;
  char* ws = (char*)d_ws;

  __bf16* Xc = (__bf16*)(ws);                    // 8192x1536 bf16   (25165824 B)
  __bf16* Wc = (__bf16*)(ws + 25165824);         // 2304x1536 bf16   ( 7077888 B)
  float*  bc = (float*) (ws + 32243712);         // 2304 f32         (    9216 B)
  __bf16* Pb = (__bf16*)(ws + 32252928);         // 768x768 bf16     ( 1179648 B)
  __bf16* Qb = (__bf16*)(ws + 33432576);         // 96x1024x64 bf16  (12582912 B)
  __bf16* Kb = (__bf16*)(ws + 46015488);         // 96x1024x64 bf16
  __bf16* Vb = (__bf16*)(ws + 58598400);         // V^T 96x64x1024 bf16
  __bf16* Xa = (__bf16*)(ws + 71181312);         // 8192x768 bf16    -> total 83764224 B

  prep_x   <<<6144, 256, 0, stream>>>(rgb, spec, Xc);
  prep_w   <<<1728, 256, 0, stream>>>(rqkvw, sqkvw, Wc);
  prep_bias<<<9,    256, 0, stream>>>(rqkvb, sqkvb, bc);
  prep_pw  <<<288,  256, 0, stream>>>(projw, Pb);

  gemm_bt<1536, 0><<<dim3(18, 64), 256, 0, stream>>>(Xc, Wc, bc, Qb, Kb, Vb, nullptr);
  attn_fwd<<<dim3(96, 4), 256, 0, stream>>>(Qb, Kb, Vb, Xa);
  gemm_bt<768, 1><<<dim3(6, 64), 256, 0, stream>>>(Xa, Pb, projb, nullptr, nullptr, nullptr, out);
}

// Round 2
// 261.913 us; speedup vs baseline: 1.2278x; 1.2278x over previous
//
#include <hip/hip_runtime.h>

#define QSCALE 0.08838834764831845f   // (2*64)^-0.5

typedef __bf16 bf16x8 __attribute__((ext_vector_type(8)));
typedef __bf16 bf16x4 __attribute__((ext_vector_type(4)));
typedef float  f32x4  __attribute__((ext_vector_type(4)));

__device__ inline bf16x8 load16(const __bf16* p) { return *reinterpret_cast<const bf16x8*>(p); }

__device__ inline void gld_lds16(const void* g, void* l) {
  __builtin_amdgcn_global_load_lds((const __attribute__((address_space(1))) void*)g,
                                   (__attribute__((address_space(3))) void*)l, 16, 0, 0);
}

// ---------------- prep kernels ----------------

// Xc [8192][1536] bf16 = concat(rgb, spec) rows
__global__ void prep_x(const float* __restrict__ rgb, const float* __restrict__ spec,
                       __bf16* __restrict__ Xc) {
  int c = blockIdx.x * 256 + threadIdx.x;       // 8192*192 chunks of 8
  int row = c / 192, seg = c % 192;
  const float* src = (seg < 96) ? (rgb + row * 768 + seg * 8)
                                : (spec + row * 768 + (seg - 96) * 8);
  bf16x8 v;
#pragma unroll
  for (int i = 0; i < 8; ++i) v[i] = (__bf16)src[i];
  *reinterpret_cast<bf16x8*>(Xc + (size_t)c * 8) = v;
}

// Wc [2304][1536] bf16 = [rgb_qkv_w * s | spec_qkv_w * t] with section scales
__global__ void prep_w(const float* __restrict__ wr, const float* __restrict__ wsp,
                       __bf16* __restrict__ Wc) {
  int c = blockIdx.x * 256 + threadIdx.x;       // 2304*192
  int n = c / 192, seg = c % 192;
  bool isR = seg < 96;
  const float* src = isR ? (wr + n * 768 + seg * 8)
                         : (wsp + n * 768 + (seg - 96) * 8);
  float sc = (n < 768) ? QSCALE : (n < 1536) ? 1.0f : (isR ? 1.0f : 0.5f);
  bf16x8 v;
#pragma unroll
  for (int i = 0; i < 8; ++i) v[i] = (__bf16)(src[i] * sc);
  *reinterpret_cast<bf16x8*>(Wc + (size_t)c * 8) = v;
}

__global__ void prep_bias(const float* __restrict__ rb, const float* __restrict__ sb,
                          float* __restrict__ bc) {
  int n = blockIdx.x * 256 + threadIdx.x;       // 2304 exactly
  float sr = (n < 768) ? QSCALE : 1.0f;
  float ss = (n < 768) ? QSCALE : (n < 1536) ? 1.0f : 0.5f;
  bc[n] = sr * rb[n] + ss * sb[n];
}

__global__ void prep_pw(const float* __restrict__ pw, __bf16* __restrict__ Pb) {
  int c = blockIdx.x * 256 + threadIdx.x;       // 768*96
  bf16x8 v;
#pragma unroll
  for (int i = 0; i < 8; ++i) v[i] = (__bf16)pw[(size_t)c * 8 + i];
  *reinterpret_cast<bf16x8*>(Pb + (size_t)c * 8) = v;
}

// ---------------- GEMM: C[M][N] = A[M][K] @ B[N][K]^T ----------------
// MODE 0: scatter to Q/K [bh][l][64] bf16 and V^T [bh][64][l] bf16 (+bias)
// MODE 1: Out f32 [M][768] = C + bias
template <int K, int MODE>
__global__ __launch_bounds__(256) void gemm_bt(const __bf16* __restrict__ A,
                                               const __bf16* __restrict__ Bm,
                                               const float* __restrict__ bias,
                                               __bf16* __restrict__ Qo, __bf16* __restrict__ Ko,
                                               __bf16* __restrict__ Vo, float* __restrict__ Out) {
  __shared__ __bf16 As[128 * 32], Bs[128 * 32];
  const int tid = threadIdx.x;
  const int m0 = blockIdx.y * 128, n0 = blockIdx.x * 128;
  const int wid = tid >> 6, lane = tid & 63, r = lane & 15, g = lane >> 4;
  const int wr = wid >> 1, wc = wid & 1;
  f32x4 acc[4][4] = {};
  const __bf16* gA = A + (size_t)(m0 + (tid >> 2)) * K + (tid & 3) * 8;
  const __bf16* gB = Bm + (size_t)(n0 + (tid >> 2)) * K + (tid & 3) * 8;
  __bf16* lA = As + wid * 512;   // wave-uniform LDS base; HW adds lane*16B
  __bf16* lB = Bs + wid * 512;

  for (int kt = 0; kt < K; kt += 32) {
    gld_lds16(gA + kt, lA);
    gld_lds16(gA + 64 * K + kt, lA + 2048);
    gld_lds16(gB + kt, lB);
    gld_lds16(gB + 64 * K + kt, lB + 2048);
    __syncthreads();
    bf16x8 af[4], bf[4];
#pragma unroll
    for (int i = 0; i < 4; ++i) af[i] = load16(&As[(wr * 64 + i * 16 + r) * 32 + g * 8]);
#pragma unroll
    for (int i = 0; i < 4; ++i) bf[i] = load16(&Bs[(wc * 64 + i * 16 + r) * 32 + g * 8]);
#pragma unroll
    for (int mi = 0; mi < 4; ++mi)
#pragma unroll
      for (int ni = 0; ni < 4; ++ni)
        acc[mi][ni] = __builtin_amdgcn_mfma_f32_16x16x32_bf16(af[mi], bf[ni], acc[mi][ni], 0, 0, 0);
    __syncthreads();
  }

  if (MODE == 0) {
    const int sec = n0 / 768;   // 128 | 768 -> block never straddles sections
#pragma unroll
    for (int mi = 0; mi < 4; ++mi)
#pragma unroll
      for (int ni = 0; ni < 4; ++ni)
#pragma unroll
        for (int j = 0; j < 4; ++j) {
          int i = m0 + wr * 64 + mi * 16 + g * 4 + j;
          int n = n0 + wc * 64 + ni * 16 + r;
          float v = acc[mi][ni][j] + bias[n];
          int b = i >> 10, l = i & 1023;
          int idx = n - sec * 768, h = idx >> 6, d = idx & 63;
          int bh = b * 12 + h;
          if (sec == 0)      Qo[(bh << 16) + (l << 6) + d] = (__bf16)v;
          else if (sec == 1) Ko[(bh << 16) + (l << 6) + d] = (__bf16)v;
          else               Vo[(bh << 16) + (d << 10) + l] = (__bf16)v;
        }
  } else {
#pragma unroll
    for (int mi = 0; mi < 4; ++mi)
#pragma unroll
      for (int ni = 0; ni < 4; ++ni)
#pragma unroll
        for (int j = 0; j < 4; ++j) {
          int i = m0 + wr * 64 + mi * 16 + g * 4 + j;
          int n = n0 + wc * 64 + ni * 16 + r;
          Out[(size_t)i * 768 + n] = acc[mi][ni][j] + bias[n];
        }
  }
}

// ---------------- flash attention (swapped QK^T, 32 q-rows/wave) ----------------
// grid (96 heads, 8 qblocks) x 256 thr. Each wave owns 32 q-rows.
// Q,K: [bh][1024][64] bf16; V: [bh][64][1024] bf16 (pre-transposed).
// Out Xo: [B=8][L=1024][768] bf16 at column h*64+d.
// S^T = K Q^T via mfma(K_frag, Q_frag): lane holds P[q=mi*16+r][kv=ni*16+g*4+j]
// -> row max/sum are 16 in-lane values + 2 cross-g shuffles; P packed to LDS
//    as bf16x4 (ds_write_b64), re-read as PV A-fragments.
__global__ __launch_bounds__(256) void attn_fwd(const __bf16* __restrict__ Qg,
                                                const __bf16* __restrict__ Kg,
                                                const __bf16* __restrict__ Vg,
                                                __bf16* __restrict__ Xo) {
  __shared__ __bf16 Pl[4][32 * 72];   // per-wave P buffer, 32 rows, stride 72
  const int bh = blockIdx.x, qb = blockIdx.y;
  const int tid = threadIdx.x, wid = tid >> 6, lane = tid & 63, r = lane & 15, g = lane >> 4;
  const int q0 = qb * 128 + wid * 32;
  const __bf16* Qh = Qg + (size_t)bh * 65536;
  const __bf16* Kh = Kg + (size_t)bh * 65536;
  const __bf16* Vh = Vg + (size_t)bh * 65536;
  __bf16* Pw = &Pl[wid][0];

  bf16x8 qf[2][2];
#pragma unroll
  for (int mi = 0; mi < 2; ++mi)
#pragma unroll
    for (int ks = 0; ks < 2; ++ks)
      qf[mi][ks] = load16(&Qh[(q0 + mi * 16 + r) * 64 + ks * 32 + g * 8]);

  f32x4 o[2][4] = {};
  float m[2] = {-1e30f, -1e30f}, l[2] = {0.f, 0.f};

  for (int kv0 = 0; kv0 < 1024; kv0 += 64) {
    // S^T = K Q^T : lane holds s[mi][ni][j] = P[q=mi*16+r][kv=kv0+ni*16+g*4+j]
    f32x4 s[2][4] = {};
#pragma unroll
    for (int ks = 0; ks < 2; ++ks) {
      bf16x8 kf[4];
#pragma unroll
      for (int ni = 0; ni < 4; ++ni) kf[ni] = load16(&Kh[(kv0 + ni * 16 + r) * 64 + ks * 32 + g * 8]);
#pragma unroll
      for (int mi = 0; mi < 2; ++mi)
#pragma unroll
        for (int ni = 0; ni < 4; ++ni)
          s[mi][ni] = __builtin_amdgcn_mfma_f32_16x16x32_bf16(kf[ni], qf[mi][ks], s[mi][ni], 0, 0, 0);
    }
    // online softmax: 16 in-lane values per q-row, cross-g reduce (xor 16, 32)
#pragma unroll
    for (int mi = 0; mi < 2; ++mi) {
      float pmax = -1e30f;
#pragma unroll
      for (int ni = 0; ni < 4; ++ni)
#pragma unroll
        for (int j = 0; j < 4; ++j) pmax = fmaxf(pmax, s[mi][ni][j]);
      pmax = fmaxf(pmax, __shfl_xor(pmax, 16, 64));
      pmax = fmaxf(pmax, __shfl_xor(pmax, 32, 64));
      float mn = fmaxf(m[mi], pmax);
      float al = __expf(m[mi] - mn);
      m[mi] = mn;
      float rs = 0.f;
#pragma unroll
      for (int ni = 0; ni < 4; ++ni) {
        bf16x4 pk;
#pragma unroll
        for (int j = 0; j < 4; ++j) {
          float p = __expf(s[mi][ni][j] - mn);
          rs += p;
          pk[j] = (__bf16)p;
        }
        *reinterpret_cast<bf16x4*>(&Pw[(mi * 16 + r) * 72 + ni * 16 + g * 4]) = pk;
      }
      rs += __shfl_xor(rs, 16, 64);
      rs += __shfl_xor(rs, 32, 64);
      l[mi] = l[mi] * al + rs;
      if (__any(al < 1.0f)) {   // skip O-rescale when running max unchanged (all lanes)
        float ab[4];
#pragma unroll
        for (int j = 0; j < 4; ++j) ab[j] = __shfl(al, g * 4 + j, 64);
#pragma unroll
        for (int di = 0; di < 4; ++di)
#pragma unroll
          for (int j = 0; j < 4; ++j) o[mi][di][j] *= ab[j];
      }
    }
    // O += P V  (A = P from per-wave LDS; B = V^T rows, contiguous in kv)
#pragma unroll
    for (int ks = 0; ks < 2; ++ks) {
      bf16x8 pa[2];
#pragma unroll
      for (int mi = 0; mi < 2; ++mi) pa[mi] = load16(&Pw[(mi * 16 + r) * 72 + ks * 32 + g * 8]);
#pragma unroll
      for (int di = 0; di < 4; ++di) {
        bf16x8 bv = load16(&Vh[(di * 16 + r) * 1024 + kv0 + ks * 32 + g * 8]);
#pragma unroll
        for (int mi = 0; mi < 2; ++mi)
          o[mi][di] = __builtin_amdgcn_mfma_f32_16x16x32_bf16(pa[mi], bv, o[mi][di], 0, 0, 0);
      }
    }
  }

  const int b = bh / 12, h = bh % 12;
#pragma unroll
  for (int mi = 0; mi < 2; ++mi) {
    float lb[4];
#pragma unroll
    for (int j = 0; j < 4; ++j) lb[j] = __shfl(l[mi], g * 4 + j, 64);
#pragma unroll
    for (int di = 0; di < 4; ++di)
#pragma unroll
      for (int j = 0; j < 4; ++j) {
        int q = q0 + mi * 16 + g * 4 + j;
        float v = o[mi][di][j] / lb[j];
        Xo[((size_t)b * 1024 + q) * 768 + h * 64 + di * 16 + r] = (__bf16)v;
      }
  }
}

// ---------------- launch ----------------

extern "C" void kernel_launch(void* const* d_in, const int* in_sizes, int n_in,
                              void* d_out, int out_size, void* d_ws, size_t ws_size,
                              hipStream_t stream) {
  const float* rgb   = (const float*)d_in[0];
  const float* spec  = (const float*)d_in[1];
  const float* rqkvw = (const float*)d_in[2];
  const float* rqkvb = (const float*)d_in[3];
  const float* sqkvw = (const float*)d_in[4];
  const float* sqkvb = (const float*)d_in[5];
  const float* projw = (const float*)d_in[6];
  const float* projb = (const float*)d_in[7];
  float* out = (float*)d_out;
  char* ws = (char*)d_ws;

  __bf16* Xc = (__bf16*)(ws);                    // 8192x1536 bf16   (25165824 B)
  __bf16* Wc = (__bf16*)(ws + 25165824);         // 2304x1536 bf16   ( 7077888 B)
  float*  bc = (float*) (ws + 32243712);         // 2304 f32         (    9216 B)
  __bf16* Pb = (__bf16*)(ws + 32252928);         // 768x768 bf16     ( 1179648 B)
  __bf16* Qb = (__bf16*)(ws + 33432576);         // 96x1024x64 bf16  (12582912 B)
  __bf16* Kb = (__bf16*)(ws + 46015488);         // 96x1024x64 bf16
  __bf16* Vb = (__bf16*)(ws + 58598400);         // V^T 96x64x1024 bf16
  __bf16* Xa = (__bf16*)(ws + 71181312);         // 8192x768 bf16    -> total 83764224 B

  prep_x   <<<6144, 256, 0, stream>>>(rgb, spec, Xc);
  prep_w   <<<1728, 256, 0, stream>>>(rqkvw, sqkvw, Wc);
  prep_bias<<<9,    256, 0, stream>>>(rqkvb, sqkvb, bc);
  prep_pw  <<<288,  256, 0, stream>>>(projw, Pb);

  gemm_bt<1536, 0><<<dim3(18, 64), 256, 0, stream>>>(Xc, Wc, bc, Qb, Kb, Vb, nullptr);
  attn_fwd<<<dim3(96, 8), 256, 0, stream>>>(Qb, Kb, Vb, Xa);
  gemm_bt<768, 1><<<dim3(6, 64), 256, 0, stream>>>(Xa, Pb, projb, nullptr, nullptr, nullptr, out);
}